// Round 10
// baseline (31.775 us; speedup 1.0000x reference)
//
#include <hip/hip_runtime.h>
#include <math.h>

// ---- problem constants ----
#define NCH    2048
#define SZ     14
#define NPOS   (SZ*SZ)         // 196
#define NQ     (NPOS/4)        // 49 float4 per channel plane
#define NB     64
#define PN     7
#define NWIN   917
#define KPER   6               // ceil(361/64) strided candidates per lane

// k1 geometry: 256 blocks (1 per CU), each sums 512 channels of one batch
#define QPB    4               // quarters per batch
#define CPB    512             // channels per block
#define F4PB   (CPB*NQ)        // 25088 float4 per block
#define TACT   980             // 20*49 active streaming threads
#define NIT    25              // 25*980 = 24500
#define TAILN  588             // 25088-24500 = 588 (24500 = 500*49)

// -------- kernel 1: full-chip channel-sum + per-quarter raw window sums ----
// Phase A: dense stream of 512 channels -> s_q[196] (proven r9 pattern).
// Phase B: windows are linear in s, so each quarter-block computes the 917
// raw window SUMS of its partial s_q; k2 just adds 4 of them. This moves the
// LDS-heavy window pass off the serial critical path into the parallel phase.
__global__ __launch_bounds__(1024) void k_chansum_win(const float4* __restrict__ x,
                                                      float* __restrict__ pw) {
  const int b = blockIdx.x;
  const int q = blockIdx.y;
  const int t = threadIdx.x;

  __shared__ float4 red[20][NQ];
  __shared__ float  s[NPOS];

  // ---- phase A: stream ----
  if (t < TACT) {
    const size_t base = (size_t)b * (NCH * NQ) + (size_t)q * F4PB;
    float ax = 0.f, ay = 0.f, az = 0.f, aw = 0.f;
#pragma unroll 5
    for (int i = 0; i < NIT; ++i) {
      const float4 v = x[base + (size_t)i * TACT + t];
      ax += v.x; ay += v.y; az += v.z; aw += v.w;
    }
    if (t < TAILN) {
      const float4 v = x[base + 24500 + t];
      ax += v.x; ay += v.y; az += v.z; aw += v.w;
    }
    float4 o; o.x = ax; o.y = ay; o.z = az; o.w = aw;
    red[t / NQ][t % NQ] = o;
  }
  __syncthreads();

  if (t < NQ) {
    float ax = 0.f, ay = 0.f, az = 0.f, aw = 0.f;
#pragma unroll
    for (int r = 0; r < 20; ++r) {
      const float4 v = red[r][t];
      ax += v.x; ay += v.y; az += v.z; aw += v.w;
    }
    s[t * 4 + 0] = ax; s[t * 4 + 1] = ay;
    s[t * 4 + 2] = az; s[t * 4 + 3] = aw;
  }
  __syncthreads();

  // ---- phase B: 917 raw window sums of this quarter ----
  if (t < NWIN) {
    const int rh[13] = {4,3,5,6,5,7,8,6,10,7,9,7,10};
    const int rw[13] = {4,5,3,6,7,5,8,10,6,9,7,10,7};
    const int wb[14] = {0,121,241,361,442,522,602,651,696,741,789,837,877,917};
    const int w = t;
    int r = 0;
    while (w >= wb[r + 1]) ++r;
    const int l  = w - wb[r];
    const int RH = rh[r], RW = rw[r];
    const int ww = SZ - RW + 1;
    const int xi = l / ww, yi = l % ww;
    float sum = 0.f;
    for (int i = 0; i < RH; ++i)
      for (int j = 0; j < RW; ++j)
        sum += s[(xi + i) * SZ + (yi + j)];
    pw[((size_t)b * QPB + q) * NWIN + w] = sum;   // raw sum; divide in k2
  }
}

// -------- kernel 2: 4-way add + coords + wave-parallel NMS (light) --------
__global__ __launch_bounds__(1024) void k_nms(const float* __restrict__ pw,
                                              float* __restrict__ out) {
  const int b    = blockIdx.x;
  const int tid  = threadIdx.x;
  const int lane = tid & 63;
  const int wave = tid >> 6;

  __shared__ float sc[NWIN];
  __shared__ float bx1[NWIN], by1[NWIN], bx2[NWIN], by2[NWIN], bar[NWIN];

  if (tid < NWIN) {
    const int rh[13] = {4,3,5,6,5,7,8,6,10,7,9,7,10};
    const int rw[13] = {4,5,3,6,7,5,8,10,6,9,7,10,7};
    const int wb[14] = {0,121,241,361,442,522,602,651,696,741,789,837,877,917};
    const int w = tid;
    int r = 0;
    while (w >= wb[r + 1]) ++r;
    const int l  = w - wb[r];
    const int RH = rh[r], RW = rw[r];
    const int ww = SZ - RW + 1;
    const int xi = l / ww, yi = l % ww;

    const float* p = pw + (size_t)b * QPB * NWIN + w;
    const float sum = p[0] + p[NWIN] + p[2 * NWIN] + p[3 * NWIN];
    const float score = sum / (float)(RH * RW);
    sc[w] = score;
    out[NB * PN * 2 + b * NWIN + w] = score;

    float x1 = (float)(xi * 32 - 1);
    float y1 = (float)(yi * 32 - 1);
    float x2 = x1 + (float)(RH * 32);
    float y2 = y1 + (float)(RW * 32);
    if (x1 < 0.f) x1 = 0.f;
    if (y1 < 0.f) y1 = 0.f;
    bx1[w] = x1; by1[w] = y1; bx2[w] = x2; by2[w] = y2;
    bar[w] = (x2 - x1 + 1.f) * (y2 - y1 + 1.f);
  }
  __syncthreads();

  if (wave < 3) {
    const int glo[3] = {0, 361, 602};
    const int ghi[3] = {361, 602, 917};
    const int gns[3] = {2, 3, 2};
    const int gob[3] = {0, 2, 5};
    const int lo = glo[wave], hi = ghi[wave];
    const int nsel = gns[wave], obase = gob[wave];

    float wk[KPER], X1[KPER], Y1[KPER], X2[KPER], Y2[KPER], AR[KPER];
#pragma unroll
    for (int k = 0; k < KPER; ++k) {
      const int j = lo + lane + k * 64;
      const bool v = j < hi;
      const int jj = v ? j : lo;
      wk[k] = v ? sc[jj] : -INFINITY;
      X1[k] = bx1[jj]; Y1[k] = by1[jj];
      X2[k] = bx2[jj]; Y2[k] = by2[jj]; AR[k] = bar[jj];
    }

    for (int st = 0; st < nsel; ++st) {
      float bv = -INFINITY; int bj = 0x7fffffff;
#pragma unroll
      for (int k = 0; k < KPER; ++k) {
        const int j = lo + lane + k * 64;
        if (wk[k] > bv) { bv = wk[k]; bj = j; }   // strict > keeps smallest j
      }
      for (int off = 32; off > 0; off >>= 1) {
        const float ov = __shfl_xor(bv, off);
        const int   oj = __shfl_xor(bj, off);
        if (ov > bv || (ov == bv && oj < bj)) { bv = ov; bj = oj; }
      }
      const float sx1 = bx1[bj], sy1 = by1[bj];
      const float sx2 = bx2[bj], sy2 = by2[bj], sar = bar[bj];
      if (lane == 0) {
        out[b * PN + obase + st]           = (float)bj;
        out[NB * PN + b * PN + obase + st] = sc[bj];
      }
#pragma unroll
      for (int k = 0; k < KPER; ++k) {
        const int j = lo + lane + k * 64;
        const float ix1 = fmaxf(X1[k], sx1);
        const float iy1 = fmaxf(Y1[k], sy1);
        const float ix2 = fminf(X2[k], sx2);
        const float iy2 = fminf(Y2[k], sy2);
        const float lw = ix2 - ix1 + 1.f;
        const float lh = iy2 - iy1 + 1.f;
        const float inter = (lw < 0.f || lh < 0.f) ? 0.f : lw * lh;
        const float iou = inter / (AR[k] + sar - inter);
        if (iou > 0.25f || j == bj) wk[k] = -INFINITY;
      }
    }
  }
}

extern "C" void kernel_launch(void* const* d_in, const int* in_sizes, int n_in,
                              void* d_out, int out_size, void* d_ws, size_t ws_size,
                              hipStream_t stream) {
  const float4* x = (const float4*)d_in[0];
  float* out = (float*)d_out;
  float* pw = (float*)d_ws;   // 64*4*917 floats = 939 KB

  dim3 g1(NB, QPB);
  k_chansum_win<<<g1, 1024, 0, stream>>>(x, pw);
  k_nms<<<NB, 1024, 0, stream>>>(pw, out);
}

// Round 11
// 31.212 us; speedup vs baseline: 1.0180x; 1.0180x over previous
//
#include <hip/hip_runtime.h>
#include <math.h>

// ---- problem constants ----
#define NCH    2048
#define SZ     14
#define NPOS   (SZ*SZ)         // 196
#define NQ     (NPOS/4)        // 49 float4 per channel plane
#define NB     64
#define PN     7
#define NWIN   917
#define KPER   6               // ceil(361/64) strided candidates per lane

// k1 geometry: 1024 blocks x 512 threads (4 blocks/CU, 32 waves/CU)
#define EPB    16              // partials (sixteenths) per batch
#define CPB    128             // channels per block
#define F4PB   (CPB*NQ)        // 6272 float4 per block
#define TACT   490             // 10*49 active streaming threads
#define NIT    12              // 12*490 = 5880 (= 120*49)
#define TAILN  392             // 6272-5880 = 392 (= 8*49)

// -------- kernel 1: max-occupancy dense channel-sum --------
// Thread t<490 reads f = base + i*490 + t; 490 % 49 == 0 keeps its plane
// position t%49 constant -> register accumulation, dense coalesced reads.
// __launch_bounds__(512,8): request 8 waves/SIMD so VGPRs cap at 64 and
// 4 blocks co-reside per CU (32 waves/CU, m13-copy-like occupancy).
__global__ __launch_bounds__(512, 8) void k_chansum(const float4* __restrict__ x,
                                                    float4* __restrict__ part4) {
  const int b = blockIdx.x;
  const int e = blockIdx.y;
  const int t = threadIdx.x;

  __shared__ float4 red[10][NQ];

  if (t < TACT) {
    const size_t base = (size_t)b * (NCH * NQ) + (size_t)e * F4PB;
    float ax = 0.f, ay = 0.f, az = 0.f, aw = 0.f;
#pragma unroll 6
    for (int i = 0; i < NIT; ++i) {
      const float4 v = x[base + (size_t)i * TACT + t];
      ax += v.x; ay += v.y; az += v.z; aw += v.w;
    }
    if (t < TAILN) {
      const float4 v = x[base + (NIT * TACT) + t];
      ax += v.x; ay += v.y; az += v.z; aw += v.w;
    }
    float4 o; o.x = ax; o.y = ay; o.z = az; o.w = aw;
    red[t / NQ][t % NQ] = o;
  }
  __syncthreads();

  if (t < NQ) {
    float ax = 0.f, ay = 0.f, az = 0.f, aw = 0.f;
#pragma unroll
    for (int r = 0; r < 10; ++r) {
      const float4 v = red[r][t];
      ax += v.x; ay += v.y; az += v.z; aw += v.w;
    }
    float4 o; o.x = ax; o.y = ay; o.z = az; o.w = aw;
    part4[((size_t)b * EPB + e) * NQ + t] = o;
  }
}

// -------- kernel 2: 16-way combine + windows + wave-parallel NMS --------
__global__ __launch_bounds__(1024) void k_nms(const float* __restrict__ part,
                                              float* __restrict__ out) {
  const int b    = blockIdx.x;
  const int tid  = threadIdx.x;
  const int lane = tid & 63;
  const int wave = tid >> 6;

  __shared__ float s[NPOS];
  __shared__ float sc[NWIN];
  __shared__ float bx1[NWIN], by1[NWIN], bx2[NWIN], by2[NWIN], bar[NWIN];

  if (tid < NPOS) {
    const float* p = part + (size_t)b * EPB * NPOS + tid;
    float acc = 0.f;
#pragma unroll
    for (int e = 0; e < EPB; ++e) acc += p[e * NPOS];
    s[tid] = acc;
  }
  __syncthreads();

  if (tid < NWIN) {
    const int rh[13] = {4,3,5,6,5,7,8,6,10,7,9,7,10};
    const int rw[13] = {4,5,3,6,7,5,8,10,6,9,7,10,7};
    const int wb[14] = {0,121,241,361,442,522,602,651,696,741,789,837,877,917};
    const int w = tid;
    int r = 0;
    while (w >= wb[r + 1]) ++r;
    const int l  = w - wb[r];
    const int RH = rh[r], RW = rw[r];
    const int ww = SZ - RW + 1;
    const int xi = l / ww, yi = l % ww;
    float sum = 0.f;
    for (int i = 0; i < RH; ++i)
      for (int j = 0; j < RW; ++j)
        sum += s[(xi + i) * SZ + (yi + j)];
    const float score = sum / (float)(RH * RW);
    sc[w] = score;
    out[NB * PN * 2 + b * NWIN + w] = score;

    float x1 = (float)(xi * 32 - 1);
    float y1 = (float)(yi * 32 - 1);
    float x2 = x1 + (float)(RH * 32);
    float y2 = y1 + (float)(RW * 32);
    if (x1 < 0.f) x1 = 0.f;
    if (y1 < 0.f) y1 = 0.f;
    bx1[w] = x1; by1[w] = y1; bx2[w] = x2; by2[w] = y2;
    bar[w] = (x2 - x1 + 1.f) * (y2 - y1 + 1.f);
  }
  __syncthreads();

  if (wave < 3) {
    const int glo[3] = {0, 361, 602};
    const int ghi[3] = {361, 602, 917};
    const int gns[3] = {2, 3, 2};
    const int gob[3] = {0, 2, 5};
    const int lo = glo[wave], hi = ghi[wave];
    const int nsel = gns[wave], obase = gob[wave];

    float wk[KPER], X1[KPER], Y1[KPER], X2[KPER], Y2[KPER], AR[KPER];
#pragma unroll
    for (int k = 0; k < KPER; ++k) {
      const int j = lo + lane + k * 64;
      const bool v = j < hi;
      const int jj = v ? j : lo;
      wk[k] = v ? sc[jj] : -INFINITY;
      X1[k] = bx1[jj]; Y1[k] = by1[jj];
      X2[k] = bx2[jj]; Y2[k] = by2[jj]; AR[k] = bar[jj];
    }

    for (int st = 0; st < nsel; ++st) {
      float bv = -INFINITY; int bj = 0x7fffffff;
#pragma unroll
      for (int k = 0; k < KPER; ++k) {
        const int j = lo + lane + k * 64;
        if (wk[k] > bv) { bv = wk[k]; bj = j; }   // strict > keeps smallest j
      }
      for (int off = 32; off > 0; off >>= 1) {
        const float ov = __shfl_xor(bv, off);
        const int   oj = __shfl_xor(bj, off);
        if (ov > bv || (ov == bv && oj < bj)) { bv = ov; bj = oj; }
      }
      const float sx1 = bx1[bj], sy1 = by1[bj];
      const float sx2 = bx2[bj], sy2 = by2[bj], sar = bar[bj];
      if (lane == 0) {
        out[b * PN + obase + st]           = (float)bj;
        out[NB * PN + b * PN + obase + st] = sc[bj];
      }
#pragma unroll
      for (int k = 0; k < KPER; ++k) {
        const int j = lo + lane + k * 64;
        const float ix1 = fmaxf(X1[k], sx1);
        const float iy1 = fmaxf(Y1[k], sy1);
        const float ix2 = fminf(X2[k], sx2);
        const float iy2 = fminf(Y2[k], sy2);
        const float lw = ix2 - ix1 + 1.f;
        const float lh = iy2 - iy1 + 1.f;
        const float inter = (lw < 0.f || lh < 0.f) ? 0.f : lw * lh;
        const float iou = inter / (AR[k] + sar - inter);
        if (iou > 0.25f || j == bj) wk[k] = -INFINITY;
      }
    }
  }
}

extern "C" void kernel_launch(void* const* d_in, const int* in_sizes, int n_in,
                              void* d_out, int out_size, void* d_ws, size_t ws_size,
                              hipStream_t stream) {
  const float4* x = (const float4*)d_in[0];
  float* out = (float*)d_out;
  float4* part4 = (float4*)d_ws;   // 64*16*49 float4 = 803 KB

  dim3 g1(NB, EPB);
  k_chansum<<<g1, 512, 0, stream>>>(x, part4);
  k_nms<<<NB, 1024, 0, stream>>>((const float*)d_ws, out);
}

// Round 12
// 29.159 us; speedup vs baseline: 1.0897x; 1.0704x over previous
//
#include <hip/hip_runtime.h>
#include <math.h>

// ---- problem constants ----
#define NCH    2048
#define SZ     14
#define NPOS   (SZ*SZ)         // 196
#define NQ     (NPOS/4)        // 49 float4 per channel plane
#define NB     64
#define PN     7
#define NWIN   917
#define KPER   6               // ceil(361/64) strided candidates per lane

// k1 geometry (r9 proven best): 256 blocks x 1024 threads, 512 ch/block
#define QPB    4               // quarters per batch
#define CPB    512             // channels per block
#define F4PB   (CPB*NQ)        // 25088 float4 per block
#define TACT   980             // 20*49 active streaming threads
#define NIT    25              // 25*980 = 24500 (= 500*49)
#define TAILN  588             // 25088-24500

typedef float f4 __attribute__((ext_vector_type(4)));

// -------- kernel 1: full-chip dense channel-sum, NON-TEMPORAL reads --------
// Identical to round 9 except x is loaded with __builtin_nontemporal_load
// (nt flag bypasses LLC allocation on the read-miss path). A/B vs r9's
// 30.8 us isolates whether Infinity-Cache allocate-on-read throttles the
// read stream to ~4.1 TB/s.
__global__ __launch_bounds__(1024) void k_chansum(const f4* __restrict__ x,
                                                  float4* __restrict__ part4) {
  const int b = blockIdx.x;
  const int q = blockIdx.y;
  const int t = threadIdx.x;

  __shared__ float4 red[20][NQ];

  if (t < TACT) {
    const size_t base = (size_t)b * (NCH * NQ) + (size_t)q * F4PB;
    float ax = 0.f, ay = 0.f, az = 0.f, aw = 0.f;
#pragma unroll 5
    for (int i = 0; i < NIT; ++i) {
      const f4 v = __builtin_nontemporal_load(&x[base + (size_t)i * TACT + t]);
      ax += v.x; ay += v.y; az += v.z; aw += v.w;
    }
    if (t < TAILN) {
      const f4 v = __builtin_nontemporal_load(&x[base + 24500 + t]);
      ax += v.x; ay += v.y; az += v.z; aw += v.w;
    }
    float4 o; o.x = ax; o.y = ay; o.z = az; o.w = aw;
    red[t / NQ][t % NQ] = o;
  }
  __syncthreads();

  if (t < NQ) {
    float ax = 0.f, ay = 0.f, az = 0.f, aw = 0.f;
#pragma unroll
    for (int r = 0; r < 20; ++r) {
      const float4 v = red[r][t];
      ax += v.x; ay += v.y; az += v.z; aw += v.w;
    }
    float4 o; o.x = ax; o.y = ay; o.z = az; o.w = aw;
    part4[((size_t)b * QPB + q) * NQ + t] = o;
  }
}

// -------- kernel 2: 4-way combine + windows + wave-parallel NMS (r9) ------
__global__ __launch_bounds__(1024) void k_nms(const float* __restrict__ part,
                                              float* __restrict__ out) {
  const int b    = blockIdx.x;
  const int tid  = threadIdx.x;
  const int lane = tid & 63;
  const int wave = tid >> 6;

  __shared__ float s[NPOS];
  __shared__ float sc[NWIN];
  __shared__ float bx1[NWIN], by1[NWIN], bx2[NWIN], by2[NWIN], bar[NWIN];

  if (tid < NPOS) {
    const float* p = part + (size_t)b * QPB * NPOS + tid;
    float acc = 0.f;
#pragma unroll
    for (int q = 0; q < QPB; ++q) acc += p[q * NPOS];
    s[tid] = acc;
  }
  __syncthreads();

  if (tid < NWIN) {
    const int rh[13] = {4,3,5,6,5,7,8,6,10,7,9,7,10};
    const int rw[13] = {4,5,3,6,7,5,8,10,6,9,7,10,7};
    const int wb[14] = {0,121,241,361,442,522,602,651,696,741,789,837,877,917};
    const int w = tid;
    int r = 0;
    while (w >= wb[r + 1]) ++r;
    const int l  = w - wb[r];
    const int RH = rh[r], RW = rw[r];
    const int ww = SZ - RW + 1;
    const int xi = l / ww, yi = l % ww;
    float sum = 0.f;
    for (int i = 0; i < RH; ++i)
      for (int j = 0; j < RW; ++j)
        sum += s[(xi + i) * SZ + (yi + j)];
    const float score = sum / (float)(RH * RW);
    sc[w] = score;
    out[NB * PN * 2 + b * NWIN + w] = score;

    float x1 = (float)(xi * 32 - 1);
    float y1 = (float)(yi * 32 - 1);
    float x2 = x1 + (float)(RH * 32);
    float y2 = y1 + (float)(RW * 32);
    if (x1 < 0.f) x1 = 0.f;
    if (y1 < 0.f) y1 = 0.f;
    bx1[w] = x1; by1[w] = y1; bx2[w] = x2; by2[w] = y2;
    bar[w] = (x2 - x1 + 1.f) * (y2 - y1 + 1.f);
  }
  __syncthreads();

  if (wave < 3) {
    const int glo[3] = {0, 361, 602};
    const int ghi[3] = {361, 602, 917};
    const int gns[3] = {2, 3, 2};
    const int gob[3] = {0, 2, 5};
    const int lo = glo[wave], hi = ghi[wave];
    const int nsel = gns[wave], obase = gob[wave];

    float wk[KPER], X1[KPER], Y1[KPER], X2[KPER], Y2[KPER], AR[KPER];
#pragma unroll
    for (int k = 0; k < KPER; ++k) {
      const int j = lo + lane + k * 64;
      const bool v = j < hi;
      const int jj = v ? j : lo;
      wk[k] = v ? sc[jj] : -INFINITY;
      X1[k] = bx1[jj]; Y1[k] = by1[jj];
      X2[k] = bx2[jj]; Y2[k] = by2[jj]; AR[k] = bar[jj];
    }

    for (int st = 0; st < nsel; ++st) {
      float bv = -INFINITY; int bj = 0x7fffffff;
#pragma unroll
      for (int k = 0; k < KPER; ++k) {
        const int j = lo + lane + k * 64;
        if (wk[k] > bv) { bv = wk[k]; bj = j; }   // strict > keeps smallest j
      }
      for (int off = 32; off > 0; off >>= 1) {
        const float ov = __shfl_xor(bv, off);
        const int   oj = __shfl_xor(bj, off);
        if (ov > bv || (ov == bv && oj < bj)) { bv = ov; bj = oj; }
      }
      const float sx1 = bx1[bj], sy1 = by1[bj];
      const float sx2 = bx2[bj], sy2 = by2[bj], sar = bar[bj];
      if (lane == 0) {
        out[b * PN + obase + st]           = (float)bj;
        out[NB * PN + b * PN + obase + st] = sc[bj];
      }
#pragma unroll
      for (int k = 0; k < KPER; ++k) {
        const int j = lo + lane + k * 64;
        const float ix1 = fmaxf(X1[k], sx1);
        const float iy1 = fmaxf(Y1[k], sy1);
        const float ix2 = fminf(X2[k], sx2);
        const float iy2 = fminf(Y2[k], sy2);
        const float lw = ix2 - ix1 + 1.f;
        const float lh = iy2 - iy1 + 1.f;
        const float inter = (lw < 0.f || lh < 0.f) ? 0.f : lw * lh;
        const float iou = inter / (AR[k] + sar - inter);
        if (iou > 0.25f || j == bj) wk[k] = -INFINITY;
      }
    }
  }
}

extern "C" void kernel_launch(void* const* d_in, const int* in_sizes, int n_in,
                              void* d_out, int out_size, void* d_ws, size_t ws_size,
                              hipStream_t stream) {
  const f4* x = (const f4*)d_in[0];
  float* out = (float*)d_out;
  float4* part4 = (float4*)d_ws;   // 256*49 float4 = 200 KB

  dim3 g1(NB, QPB);
  k_chansum<<<g1, 1024, 0, stream>>>(x, part4);
  k_nms<<<NB, 1024, 0, stream>>>((const float*)d_ws, out);
}